// Round 4
// baseline (625.749 us; speedup 1.0000x reference)
//
#include <hip/hip_runtime.h>
#include <stdint.h>
#include <math.h>

// (B,H,SQ,SK,D,DV) = (2,16,2048,2048,64,64)
// out = (softmax(q k^T) * 0.5) with dropout p=0.1 (jax x64 threefry key 42) @ v
// R14: kill the staging pipeline. Counter audit showed derived VALUBusy/MfmaUtil
// use gfx94x weights (true VALU ~37%, true MFMA ~2.5%) -> kernel was STALL-bound:
// per-tile barrier + vmcnt(0) drain exposed full L2 latency 16x per block, and
// 48 KB LDS capped residency at 3 blocks/CU vs a 4/CU grid.
// Fix: prep already writes K/Kl/Vt in the exact per-lane swizzled fragment
// layout -> load MFMA fragments DIRECTLY from global (L2-resident: 3 MB/XCD via
// XCD swizzle). No staging, no in-loop barriers, LDS = 18.7 KB merge only,
// 4 blocks/CU, 8 waves/SIMD (launch_bounds(512,8) caps VGPR at 64).
// Mask (verified bit-exact, R13): bits64(i) = (o0<<32)|o1 of threefry((0,42),(0,i)),
// i = global flat (b,h,q,k); keep iff bits64 < 0xE666666666667000 (0.9_f64).
namespace {
constexpr int Bb = 2, Hh = 16, SQc = 2048, SKc = 2048, Dc = 64, DVc = 64;
constexpr int TK = 64;
constexpr float LOG2E = 1.4426950408889634f;
constexpr uint64_t KEEP_T = 0xE666666666667000ull;  // 0.9_f64 threshold, exact

typedef __attribute__((ext_vector_type(8))) short short8;   // MFMA A/B frag (8 bf16)
typedef __attribute__((ext_vector_type(4))) float f32x4;    // MFMA C/D frag

__device__ __forceinline__ uint32_t rotl_(uint32_t x, int r) {
  return __builtin_amdgcn_alignbit(x, x, 32 - r);  // 1-instr rotate
}

// threefry2x32, key=(0,42), counter=(0, i): returns (o0 << 32) | o1.
// Injection adds fused with the following round's x0-add (v_add3_u32); mod-2^32
// associativity keeps it bit-exact vs the textbook form. VERIFIED R13.
__device__ __forceinline__ uint64_t tf_bits64(uint32_t ctr) {
  const uint32_t KS1 = 42u, KS2 = 0x1BD11BF0u;  // 0x1BD11BDA ^ 42
  uint32_t x0, x1;
  x1 = ctr + KS1;
  // group 1 (rot 13,15,26,6); x0 starts at 0 so first add folds
  x0 = x1;        x1 = rotl_(x1, 13); x1 ^= x0;
  x0 += x1;       x1 = rotl_(x1, 15); x1 ^= x0;
  x0 += x1;       x1 = rotl_(x1, 26); x1 ^= x0;
  x0 += x1;       x1 = rotl_(x1,  6); x1 ^= x0;
  // inject (KS1, KS2+1), fused
  x1 += KS2 + 1u;
  x0 += KS1 + x1; x1 = rotl_(x1, 17); x1 ^= x0;
  x0 += x1;       x1 = rotl_(x1, 29); x1 ^= x0;
  x0 += x1;       x1 = rotl_(x1, 16); x1 ^= x0;
  x0 += x1;       x1 = rotl_(x1, 24); x1 ^= x0;
  // inject (KS2, 0+2), fused
  x1 += 2u;
  x0 += KS2 + x1; x1 = rotl_(x1, 13); x1 ^= x0;
  x0 += x1;       x1 = rotl_(x1, 15); x1 ^= x0;
  x0 += x1;       x1 = rotl_(x1, 26); x1 ^= x0;
  x0 += x1;       x1 = rotl_(x1,  6); x1 ^= x0;
  // inject (0, KS1+3)
  x1 += KS1 + 3u;
  x0 += x1;       x1 = rotl_(x1, 17); x1 ^= x0;
  x0 += x1;       x1 = rotl_(x1, 29); x1 ^= x0;
  x0 += x1;       x1 = rotl_(x1, 16); x1 ^= x0;
  x0 += x1;       x1 = rotl_(x1, 24); x1 ^= x0;
  // inject (KS1, KS2+4), fused
  x1 += KS2 + 4u;
  x0 += KS1 + x1; x1 = rotl_(x1, 13); x1 ^= x0;
  x0 += x1;       x1 = rotl_(x1, 15); x1 ^= x0;
  x0 += x1;       x1 = rotl_(x1, 26); x1 ^= x0;
  x0 += x1;       x1 = rotl_(x1,  6); x1 ^= x0;
  // final inject (KS2, 0+5); o0 is the HIGH word (jax 64-bit combine)
  return ((uint64_t)(x0 + KS2) << 32) | (uint64_t)(x1 + 5u);
}

__device__ __forceinline__ uint32_t f2bf_u(float x) {  // RNE bf16 (finite x), low 16 bits
  uint32_t u = __float_as_uint(x);
  u += 0x7FFFu + ((u >> 16) & 1u);
  return u >> 16;
}
}  // namespace

// Pre-pass: tile-contiguous, XOR-swizzled layouts (the per-lane MFMA fragment
// image — consumed directly from global by attn_main).
// Kh/Kl tile (h,kt): shorts[4096]; elem (row,col): row*64 + ((col>>3)^(row&7))*8 + (col&7)
// Vt tile  (h,kt): shorts[4096]; elem (dv,skl) = V[kt*64+skl][dv], same swizzle on skl.
__global__ __launch_bounds__(256) void prep_kernel(
    const float* __restrict__ k, const float* __restrict__ v,
    unsigned short* __restrict__ Khg, unsigned short* __restrict__ Klg,
    unsigned short* __restrict__ Vtg) {
  __shared__ float Vs[64 * 65];
  const int t = threadIdx.x;
  const int h = blockIdx.x >> 5;
  const int kt = blockIdx.x & 31;
  const size_t src = ((size_t)h * SKc + kt * 64) * Dc;
  const size_t tb = (size_t)(h * 32 + kt) * 4096;  // tile base (shorts)
#pragma unroll
  for (int i = 0; i < 4; ++i) {
    int idx = t + 256 * i;
    int row = idx >> 4, d0 = (idx & 15) << 2;
    float4 kv = *(const float4*)(k + src + row * Dc + d0);
    uint32_t hx = f2bf_u(kv.x), hy = f2bf_u(kv.y), hz = f2bf_u(kv.z), hw = f2bf_u(kv.w);
    uint32_t lx = f2bf_u(kv.x - __uint_as_float(hx << 16));
    uint32_t ly = f2bf_u(kv.y - __uint_as_float(hy << 16));
    uint32_t lz = f2bf_u(kv.z - __uint_as_float(hz << 16));
    uint32_t lw = f2bf_u(kv.w - __uint_as_float(hw << 16));
    int phys = row * 64 + (((d0 >> 3) ^ (row & 7)) << 3) + (d0 & 7);
    *(ushort4*)(Khg + tb + phys) =
        make_ushort4((unsigned short)hx, (unsigned short)hy, (unsigned short)hz, (unsigned short)hw);
    *(ushort4*)(Klg + tb + phys) =
        make_ushort4((unsigned short)lx, (unsigned short)ly, (unsigned short)lz, (unsigned short)lw);
    float4 vv = *(const float4*)(v + src + row * Dc + d0);  // DVc == Dc
    *(float4*)(&Vs[row * 65 + d0]) = vv;
  }
  __syncthreads();
  const int dv = t >> 2;
  const int j0 = (t & 3) << 1;  // two sk-chunks per thread
#pragma unroll
  for (int g = 0; g < 2; ++g) {
    int chunk = j0 + g;
    unsigned short tmp[8];
#pragma unroll
    for (int s = 0; s < 8; ++s)
      tmp[s] = (unsigned short)f2bf_u(Vs[(chunk * 8 + s) * 65 + dv]);
    *(short8*)(Vtg + tb + dv * 64 + ((chunk ^ (dv & 7)) << 3)) = *(const short8*)tmp;
  }
}

__global__ __launch_bounds__(512, 8) void attn_main(
    const float* __restrict__ q, const unsigned short* __restrict__ Khg,
    const unsigned short* __restrict__ Klg, const unsigned short* __restrict__ Vtg,
    float* __restrict__ out) {
  // LDS: merge buffers only (18.7 KB) -> 4 blocks/CU, 32 waves/CU, no grid tail.
  __shared__ __align__(16) float Lacc[4][16][72];  // [qsub][lm][dv] 18432 B
  __shared__ float Ll[64];

  const int t = threadIdx.x;
  const int lane = t & 63;
  const int w = t >> 6;        // 8 waves
  const int lm = lane & 15;
  const int quad = lane >> 4;
  const int khalf = w & 1;     // k-half this wave processes
  const int qsub = w >> 1;     // q-row group 0..3

  // XCD swizzle: 128 consecutive vids (4 heads) per XCD -> K/V tiles L2-resident
  const int vid = (blockIdx.x & 7) * 128 + (blockIdx.x >> 3);
  const int qt = vid & 31;            // 32 q-tiles of 64 rows
  const int h = (vid >> 5) & 15;
  const int b = vid >> 9;
  const int qrow = qt * 64 + qsub * 16 + lm;

  // ---- Q B-frags (fp32 * log2e -> split bf16 in regs), constant over k-loop ----
  short8 qh[2], ql[2];
  {
    const float* qp = q + (((size_t)(b * Hh + h)) * SQc + qrow) * Dc;
#pragma unroll
    for (int c = 0; c < 2; ++c) {
#pragma unroll
      for (int j2 = 0; j2 < 2; ++j2) {
        float4 x = *(const float4*)(qp + c * 32 + quad * 8 + j2 * 4);
        float xs[4] = {x.x * LOG2E, x.y * LOG2E, x.z * LOG2E, x.w * LOG2E};
#pragma unroll
        for (int j = 0; j < 4; ++j) {
          uint32_t hb = f2bf_u(xs[j]);
          float lo = xs[j] - __uint_as_float(hb << 16);
          qh[c][j2 * 4 + j] = (short)hb;
          ql[c][j2 * 4 + j] = (short)f2bf_u(lo);
        }
      }
    }
  }

  // per-group tile pointers (advance 4096 shorts = 8192 B per tile)
  const size_t tsh = (size_t)(h * 32 + khalf * 16) * 4096;
  const unsigned short* pKh = Khg + tsh;
  const unsigned short* pKl = Klg + tsh;
  const unsigned short* pVt = Vtg + tsh;

  f32x4 acc[4] = {{0.f, 0.f, 0.f, 0.f}, {0.f, 0.f, 0.f, 0.f},
                  {0.f, 0.f, 0.f, 0.f}, {0.f, 0.f, 0.f, 0.f}};
  float l_i = 0.f;  // fixed-m (m=0) partial denominator

  // swizzled per-lane fragment offsets (shorts), loop-invariant
  const int e = lm & 7;
  const int a0s = lm * 64 + ((quad ^ e) << 3);        // chunks 0..3
  const int a1s = lm * 64 + (((quad + 4) ^ e) << 3);  // chunks 4..7

  // bpermute byte-addresses for the cross-quad P exchange (constant per lane)
  const int pa0 = ((quad & 1) * 32 + lm) << 2;
  const int pa1 = pa0 + 64;
  const uint32_t sel = (quad >= 2) ? 0x07060302u : 0x05040100u;

  // GLOBAL flat (b,h,q,k) index for the counter (0, i)
  uint32_t ctile = ((uint32_t)((b * Hh + h) * SQc + qrow)) * (uint32_t)SKc +
                   (uint32_t)(khalf * 16 * TK + quad * 4);

#pragma unroll 1
  for (int i = 0; i < 16; ++i, ctile += TK, pKh += 4096, pKl += 4096, pVt += 4096) {
#pragma unroll
    for (int c = 0; c < 2; ++c) {
      // ---- S^T for K-rows (2c)*16+lm, (2c+1)*16+lm : 3-term split bf16;
      //      fragments straight from L2 (global is the swizzled LDS image) ----
      f32x4 s0 = {0.f, 0.f, 0.f, 0.f}, s1 = {0.f, 0.f, 0.f, 0.f};
#pragma unroll
      for (int d = 0; d < 2; ++d) {
        const int ad = (d == 0) ? a0s : a1s;
        short8 kh0 = *(const short8*)&pKh[ad + (2 * c) * 1024];
        short8 kl0 = *(const short8*)&pKl[ad + (2 * c) * 1024];
        s0 = __builtin_amdgcn_mfma_f32_16x16x32_bf16(kh0, qh[d], s0, 0, 0, 0);
        s0 = __builtin_amdgcn_mfma_f32_16x16x32_bf16(kl0, qh[d], s0, 0, 0, 0);
        s0 = __builtin_amdgcn_mfma_f32_16x16x32_bf16(kh0, ql[d], s0, 0, 0, 0);
        short8 kh1 = *(const short8*)&pKh[ad + (2 * c + 1) * 1024];
        short8 kl1 = *(const short8*)&pKl[ad + (2 * c + 1) * 1024];
        s1 = __builtin_amdgcn_mfma_f32_16x16x32_bf16(kh1, qh[d], s1, 0, 0, 0);
        s1 = __builtin_amdgcn_mfma_f32_16x16x32_bf16(kl1, qh[d], s1, 0, 0, 0);
        s1 = __builtin_amdgcn_mfma_f32_16x16x32_bf16(kh1, ql[d], s1, 0, 0, 0);
      }

      // ---- p = exp2(s) (Q pre-scaled by log2e; fixed m, fp32-safe);
      //      x64 threefry dropout (u64 compare) as float cndmask;
      //      HW pack v_cvt_pk_bf16_f32 ----
      uint32_t pkc[4];
#pragma unroll
      for (int r = 0; r < 4; ++r) {
        float p0 = __builtin_amdgcn_exp2f(s0[r]);
        float p1 = __builtin_amdgcn_exp2f(s1[r]);
        l_i += p0 + p1;  // denominator over UNdropped probs
        uint64_t b0 = tf_bits64(ctile + (uint32_t)(c * 32 + r));
        uint64_t b1 = tf_bits64(ctile + (uint32_t)(c * 32 + 16 + r));
        float k0 = (b0 < KEEP_T) ? p0 : 0.0f;
        float k1 = (b1 < KEEP_T) ? p1 : 0.0f;
        uint32_t pk;
        asm("v_cvt_pk_bf16_f32 %0, %1, %2" : "=v"(pk) : "v"(k0), "v"(k1));
        pkc[r] = pk;  // (bf16(k1)<<16)|bf16(k0), RNE
      }

      // ---- P^T B-frag via cross-quad bpermute (no barrier) ----
      short8 pb;
      {
        uint32_t e0 = (uint32_t)__builtin_amdgcn_ds_bpermute(pa0, (int)pkc[0]);
        uint32_t e1 = (uint32_t)__builtin_amdgcn_ds_bpermute(pa0, (int)pkc[1]);
        uint32_t e2 = (uint32_t)__builtin_amdgcn_ds_bpermute(pa0, (int)pkc[2]);
        uint32_t e3 = (uint32_t)__builtin_amdgcn_ds_bpermute(pa0, (int)pkc[3]);
        uint32_t f0 = (uint32_t)__builtin_amdgcn_ds_bpermute(pa1, (int)pkc[0]);
        uint32_t f1 = (uint32_t)__builtin_amdgcn_ds_bpermute(pa1, (int)pkc[1]);
        uint32_t f2 = (uint32_t)__builtin_amdgcn_ds_bpermute(pa1, (int)pkc[2]);
        uint32_t f3 = (uint32_t)__builtin_amdgcn_ds_bpermute(pa1, (int)pkc[3]);
        uint32_t w0 = __builtin_amdgcn_perm(e1, e0, sel);
        uint32_t w1 = __builtin_amdgcn_perm(e3, e2, sel);
        uint32_t w2 = __builtin_amdgcn_perm(f1, f0, sel);
        uint32_t w3 = __builtin_amdgcn_perm(f3, f2, sel);
        uint32_t tmp[4] = {w0, w1, w2, w3};
        pb = *(const short8*)tmp;  // B[k=quad*8+j][n=lm] for sk-chunk c
      }

      // ---- O^T += V^T(chunk c) . P^T(chunk c), V^T frags from L2 ----
      {
        const int ac = (c == 0) ? a0s : a1s;
#pragma unroll
        for (int nb = 0; nb < 4; ++nb) {
          short8 vb = *(const short8*)&pVt[ac + nb * 1024];
          acc[nb] = __builtin_amdgcn_mfma_f32_16x16x32_bf16(vb, pb, acc[nb], 0, 0, 0);
        }
      }
    }
  }

  // ---- reduce l across quads ----
  l_i += __shfl_xor(l_i, 16);
  l_i += __shfl_xor(l_i, 32);

  // ---- combine the two k-halves via LDS (merge-only shared memory) ----
  if (khalf == 1) {
#pragma unroll
    for (int nb = 0; nb < 4; ++nb)
      *(f32x4*)&Lacc[qsub][lm][nb * 16 + quad * 4] = acc[nb];
    if (quad == 0) Ll[qsub * 16 + lm] = l_i;
  }
  __syncthreads();
  if (khalf == 0) {
    float lt = l_i + Ll[qsub * 16 + lm];
    float sc = (0.5f / 0.9f) / lt;
    float* op = out + (((size_t)(b * Hh + h)) * SQc + qrow) * DVc;
#pragma unroll
    for (int nb = 0; nb < 4; ++nb) {
      f32x4 other = *(const f32x4*)&Lacc[qsub][lm][nb * 16 + quad * 4];
      float4 o = make_float4((acc[nb][0] + other[0]) * sc, (acc[nb][1] + other[1]) * sc,
                             (acc[nb][2] + other[2]) * sc, (acc[nb][3] + other[3]) * sc);
      *(float4*)(op + nb * 16 + quad * 4) = o;
    }
  }
}

extern "C" void kernel_launch(void* const* d_in, const int* in_sizes, int n_in,
                              void* d_out, int out_size, void* d_ws, size_t ws_size,
                              hipStream_t stream) {
  const float* q = (const float*)d_in[0];
  const float* k = (const float*)d_in[1];
  const float* v = (const float*)d_in[2];
  float* out = (float*)d_out;
  // ws layout: Kh (4 MB) | Kl (4 MB) | Vt (4 MB), tile-contiguous swizzled
  unsigned short* Khg = (unsigned short*)d_ws;
  unsigned short* Klg = Khg + (size_t)Hh * SKc * Dc;
  unsigned short* Vtg = Klg + (size_t)Hh * SKc * Dc;
  prep_kernel<<<dim3(Hh * 32), 256, 0, stream>>>(k, v, Khg, Klg, Vtg);
  attn_main<<<dim3(Bb * Hh * (SQc / 64)), 512, 0, stream>>>(q, Khg, Klg, Vtg, out);
}

// Round 5
// 358.387 us; speedup vs baseline: 1.7460x; 1.7460x over previous
//
#include <hip/hip_runtime.h>
#include <stdint.h>
#include <math.h>

// (B,H,SQ,SK,D,DV) = (2,16,2048,2048,64,64)
// out = (softmax(q k^T) * 0.5) with dropout p=0.1 (jax x64 threefry key 42) @ v
// R15: R14 post-mortem — direct-from-global fragments thrashed L2 (FETCH 20->780MB).
// Revert to LDS staging (R13 layout, verified) but fix its two measured losses:
//  (a) per-tile vmcnt(0) drain: now double-buffered, stage tile i+1 issued BEFORE
//      compute of tile i -> drain happens one full compute phase (~2200 cyc) later.
//      One barrier per tile (was 2).
//  (b) 54% occupancy tail (1024 blocks @ 3-residency): now 128 q-rows/block,
//      grid 512 = exactly 2 blocks/CU, all resident, zero tail. All 8 waves share
//      each k-tile; each wave owns its 16 q-rows across ALL k -> no merge epilogue.
// Mask (verified bit-exact, R13): bits64(i) = (o0<<32)|o1 of threefry((0,42),(0,i)),
// i = global flat (b,h,q,k); keep iff bits64 < 0xE666666666667000 (0.9_f64).
namespace {
constexpr int Bb = 2, Hh = 16, SQc = 2048, SKc = 2048, Dc = 64, DVc = 64;
constexpr int TK = 64;
constexpr float LOG2E = 1.4426950408889634f;
constexpr uint64_t KEEP_T = 0xE666666666667000ull;  // 0.9_f64 threshold, exact

typedef __attribute__((ext_vector_type(8))) short short8;   // MFMA A/B frag (8 bf16)
typedef __attribute__((ext_vector_type(4))) float f32x4;    // MFMA C/D frag

__device__ __forceinline__ uint32_t rotl_(uint32_t x, int r) {
  return __builtin_amdgcn_alignbit(x, x, 32 - r);  // 1-instr rotate
}

// threefry2x32, key=(0,42), counter=(0, i): returns (o0 << 32) | o1.
// Injection adds fused with the following round's x0-add (v_add3_u32); mod-2^32
// associativity keeps it bit-exact vs the textbook form. VERIFIED R13.
__device__ __forceinline__ uint64_t tf_bits64(uint32_t ctr) {
  const uint32_t KS1 = 42u, KS2 = 0x1BD11BF0u;  // 0x1BD11BDA ^ 42
  uint32_t x0, x1;
  x1 = ctr + KS1;
  // group 1 (rot 13,15,26,6); x0 starts at 0 so first add folds
  x0 = x1;        x1 = rotl_(x1, 13); x1 ^= x0;
  x0 += x1;       x1 = rotl_(x1, 15); x1 ^= x0;
  x0 += x1;       x1 = rotl_(x1, 26); x1 ^= x0;
  x0 += x1;       x1 = rotl_(x1,  6); x1 ^= x0;
  // inject (KS1, KS2+1), fused
  x1 += KS2 + 1u;
  x0 += KS1 + x1; x1 = rotl_(x1, 17); x1 ^= x0;
  x0 += x1;       x1 = rotl_(x1, 29); x1 ^= x0;
  x0 += x1;       x1 = rotl_(x1, 16); x1 ^= x0;
  x0 += x1;       x1 = rotl_(x1, 24); x1 ^= x0;
  // inject (KS2, 0+2), fused
  x1 += 2u;
  x0 += KS2 + x1; x1 = rotl_(x1, 13); x1 ^= x0;
  x0 += x1;       x1 = rotl_(x1, 15); x1 ^= x0;
  x0 += x1;       x1 = rotl_(x1, 26); x1 ^= x0;
  x0 += x1;       x1 = rotl_(x1,  6); x1 ^= x0;
  // inject (0, KS1+3)
  x1 += KS1 + 3u;
  x0 += x1;       x1 = rotl_(x1, 17); x1 ^= x0;
  x0 += x1;       x1 = rotl_(x1, 29); x1 ^= x0;
  x0 += x1;       x1 = rotl_(x1, 16); x1 ^= x0;
  x0 += x1;       x1 = rotl_(x1, 24); x1 ^= x0;
  // inject (KS1, KS2+4), fused
  x1 += KS2 + 4u;
  x0 += KS1 + x1; x1 = rotl_(x1, 13); x1 ^= x0;
  x0 += x1;       x1 = rotl_(x1, 15); x1 ^= x0;
  x0 += x1;       x1 = rotl_(x1, 26); x1 ^= x0;
  x0 += x1;       x1 = rotl_(x1,  6); x1 ^= x0;
  // final inject (KS2, 0+5); o0 is the HIGH word (jax 64-bit combine)
  return ((uint64_t)(x0 + KS2) << 32) | (uint64_t)(x1 + 5u);
}

__device__ __forceinline__ uint32_t f2bf_u(float x) {  // RNE bf16 (finite x), low 16 bits
  uint32_t u = __float_as_uint(x);
  u += 0x7FFFu + ((u >> 16) & 1u);
  return u >> 16;
}

// async global->LDS, 16 B per lane; LDS base wave-uniform, global addr per-lane
__device__ __forceinline__ void gl_lds16(const void* g, void* l) {
  __builtin_amdgcn_global_load_lds(
      (const __attribute__((address_space(1))) unsigned int*)g,
      (__attribute__((address_space(3))) unsigned int*)l, 16, 0, 0);
}
}  // namespace

// Pre-pass: tile-contiguous, XOR-swizzled layouts.
// Kh/Kl tile (h,kt): shorts[4096]; elem (row,col): row*64 + ((col>>3)^(row&7))*8 + (col&7)
// Vt tile  (h,kt): shorts[4096]; elem (dv,skl) = V[kt*64+skl][dv], same swizzle on skl.
__global__ __launch_bounds__(256) void prep_kernel(
    const float* __restrict__ k, const float* __restrict__ v,
    unsigned short* __restrict__ Khg, unsigned short* __restrict__ Klg,
    unsigned short* __restrict__ Vtg) {
  __shared__ float Vs[64 * 65];
  const int t = threadIdx.x;
  const int h = blockIdx.x >> 5;
  const int kt = blockIdx.x & 31;
  const size_t src = ((size_t)h * SKc + kt * 64) * Dc;
  const size_t tb = (size_t)(h * 32 + kt) * 4096;  // tile base (shorts)
#pragma unroll
  for (int i = 0; i < 4; ++i) {
    int idx = t + 256 * i;
    int row = idx >> 4, d0 = (idx & 15) << 2;
    float4 kv = *(const float4*)(k + src + row * Dc + d0);
    uint32_t hx = f2bf_u(kv.x), hy = f2bf_u(kv.y), hz = f2bf_u(kv.z), hw = f2bf_u(kv.w);
    uint32_t lx = f2bf_u(kv.x - __uint_as_float(hx << 16));
    uint32_t ly = f2bf_u(kv.y - __uint_as_float(hy << 16));
    uint32_t lz = f2bf_u(kv.z - __uint_as_float(hz << 16));
    uint32_t lw = f2bf_u(kv.w - __uint_as_float(hw << 16));
    int phys = row * 64 + (((d0 >> 3) ^ (row & 7)) << 3) + (d0 & 7);
    *(ushort4*)(Khg + tb + phys) =
        make_ushort4((unsigned short)hx, (unsigned short)hy, (unsigned short)hz, (unsigned short)hw);
    *(ushort4*)(Klg + tb + phys) =
        make_ushort4((unsigned short)lx, (unsigned short)ly, (unsigned short)lz, (unsigned short)lw);
    float4 vv = *(const float4*)(v + src + row * Dc + d0);  // DVc == Dc
    *(float4*)(&Vs[row * 65 + d0]) = vv;
  }
  __syncthreads();
  const int dv = t >> 2;
  const int j0 = (t & 3) << 1;  // two sk-chunks per thread
#pragma unroll
  for (int g = 0; g < 2; ++g) {
    int chunk = j0 + g;
    unsigned short tmp[8];
#pragma unroll
    for (int s = 0; s < 8; ++s)
      tmp[s] = (unsigned short)f2bf_u(Vs[(chunk * 8 + s) * 65 + dv]);
    *(short8*)(Vtg + tb + dv * 64 + ((chunk ^ (dv & 7)) << 3)) = *(const short8*)tmp;
  }
}

__global__ __launch_bounds__(512, 4) void attn_main(
    const float* __restrict__ q, const unsigned short* __restrict__ Khg,
    const unsigned short* __restrict__ Klg, const unsigned short* __restrict__ Vtg,
    float* __restrict__ out) {
  // double-buffered staging: each buffer Kh [0,4096) Kl [4096,8192) Vt [8192,12288)
  // shorts; 24 KB x2 = 48 KB. 8 waves all consume the same tile.
  __shared__ __align__(16) unsigned short stag[2][12288];

  const int t = threadIdx.x;
  const int lane = t & 63;
  const int w = t >> 6;        // 8 waves = 8 q-row groups of 16
  const int lm = lane & 15;
  const int quad = lane >> 4;

  // XCD swizzle: 64 consecutive vids (4 heads) per XCD -> K/V tiles L2-resident
  const int vid = (blockIdx.x & 7) * 64 + (blockIdx.x >> 3);
  const int qt = vid & 15;            // 16 q-tiles of 128 rows
  const int h = (vid >> 4) & 15;
  const int b = vid >> 8;
  const int qrow = qt * 128 + w * 16 + lm;

  // ---- Q B-frags (fp32 * log2e -> split bf16 in regs), constant over k-loop ----
  short8 qh[2], ql[2];
  {
    const float* qp = q + (((size_t)(b * Hh + h)) * SQc + qrow) * Dc;
#pragma unroll
    for (int c = 0; c < 2; ++c) {
#pragma unroll
      for (int j2 = 0; j2 < 2; ++j2) {
        float4 x = *(const float4*)(qp + c * 32 + quad * 8 + j2 * 4);
        float xs[4] = {x.x * LOG2E, x.y * LOG2E, x.z * LOG2E, x.w * LOG2E};
#pragma unroll
        for (int j = 0; j < 4; ++j) {
          uint32_t hb = f2bf_u(xs[j]);
          float lo = xs[j] - __uint_as_float(hb << 16);
          qh[c][j2 * 4 + j] = (short)hb;
          ql[c][j2 * 4 + j] = (short)f2bf_u(lo);
        }
      }
    }
  }

  const char* kh_t = (const char*)Khg + (size_t)(h * 32) * 8192;
  const char* kl_t = (const char*)Klg + (size_t)(h * 32) * 8192;
  const char* vt_t = (const char*)Vtg + (size_t)(h * 32) * 8192;

  f32x4 acc[4] = {{0.f, 0.f, 0.f, 0.f}, {0.f, 0.f, 0.f, 0.f},
                  {0.f, 0.f, 0.f, 0.f}, {0.f, 0.f, 0.f, 0.f}};
  float l_i = 0.f;  // fixed-m (m=0) partial denominator

  // swizzled LDS read offsets (shorts), loop-invariant
  const int e = lm & 7;
  const int a0s = lm * 64 + ((quad ^ e) << 3);        // chunks 0..3
  const int a1s = lm * 64 + (((quad + 4) ^ e) << 3);  // chunks 4..7

  // bpermute byte-addresses for the cross-quad P exchange (constant per lane)
  const int pa0 = ((quad & 1) * 32 + lm) << 2;
  const int pa1 = pa0 + 64;
  const uint32_t sel = (quad >= 2) ? 0x07060302u : 0x05040100u;

  // GLOBAL flat (b,h,q,k) index for the counter (0, i)
  uint32_t ctile = ((uint32_t)((b * Hh + h) * SQc + qrow)) * (uint32_t)SKc +
                   (uint32_t)(quad * 4);

  // staging offset for this wave (3 KB of the 24 KB tile)
  const int soff = w * 1024 + lane * 16;

  // ---- prologue: stage tile 0 into stag[0] ----
  {
    char* db = (char*)&stag[0][0];
    gl_lds16(kh_t + soff, db + soff);
    gl_lds16(kl_t + soff, db + 8192 + soff);
    gl_lds16(vt_t + soff, db + 16384 + soff);
  }

#pragma unroll 1
  for (int i = 0; i < 32; ++i, ctile += TK) {
    // barrier: (a) drains this wave's staging issued last iter (tile i ready),
    // (b) all waves done reading the buffer tile i+1 will overwrite.
    __syncthreads();
    // ---- issue next tile's staging into the other buffer (drained NEXT iter) ----
    if (i < 31) {
      const size_t tile = (size_t)(i + 1) * 8192;
      char* db = (char*)&stag[(i & 1) ^ 1][0];
      gl_lds16(kh_t + tile + soff, db + soff);
      gl_lds16(kl_t + tile + soff, db + 8192 + soff);
      gl_lds16(vt_t + tile + soff, db + 16384 + soff);
    }
    const unsigned short* sb = &stag[i & 1][0];

#pragma unroll
    for (int c = 0; c < 2; ++c) {
      // ---- S^T for K-rows of chunk c : 3-term split bf16 ----
      f32x4 s0 = {0.f, 0.f, 0.f, 0.f}, s1 = {0.f, 0.f, 0.f, 0.f};
#pragma unroll
      for (int d = 0; d < 2; ++d) {
        const int ad = (d == 0) ? a0s : a1s;
        short8 kh0 = *(const short8*)&sb[ad + (2 * c) * 1024];
        short8 kl0 = *(const short8*)&sb[ad + (2 * c) * 1024 + 4096];
        s0 = __builtin_amdgcn_mfma_f32_16x16x32_bf16(kh0, qh[d], s0, 0, 0, 0);
        s0 = __builtin_amdgcn_mfma_f32_16x16x32_bf16(kl0, qh[d], s0, 0, 0, 0);
        s0 = __builtin_amdgcn_mfma_f32_16x16x32_bf16(kh0, ql[d], s0, 0, 0, 0);
        short8 kh1 = *(const short8*)&sb[ad + (2 * c + 1) * 1024];
        short8 kl1 = *(const short8*)&sb[ad + (2 * c + 1) * 1024 + 4096];
        s1 = __builtin_amdgcn_mfma_f32_16x16x32_bf16(kh1, qh[d], s1, 0, 0, 0);
        s1 = __builtin_amdgcn_mfma_f32_16x16x32_bf16(kl1, qh[d], s1, 0, 0, 0);
        s1 = __builtin_amdgcn_mfma_f32_16x16x32_bf16(kh1, ql[d], s1, 0, 0, 0);
      }

      // ---- p = exp2(s) (Q pre-scaled by log2e; fixed m, fp32-safe);
      //      x64 threefry dropout (u64 compare) as float cndmask;
      //      HW pack v_cvt_pk_bf16_f32 ----
      uint32_t pkc[4];
#pragma unroll
      for (int r = 0; r < 4; ++r) {
        float p0 = __builtin_amdgcn_exp2f(s0[r]);
        float p1 = __builtin_amdgcn_exp2f(s1[r]);
        l_i += p0 + p1;  // denominator over UNdropped probs
        uint64_t b0 = tf_bits64(ctile + (uint32_t)(c * 32 + r));
        uint64_t b1 = tf_bits64(ctile + (uint32_t)(c * 32 + 16 + r));
        float k0 = (b0 < KEEP_T) ? p0 : 0.0f;
        float k1 = (b1 < KEEP_T) ? p1 : 0.0f;
        uint32_t pk;
        asm("v_cvt_pk_bf16_f32 %0, %1, %2" : "=v"(pk) : "v"(k0), "v"(k1));
        pkc[r] = pk;  // (bf16(k1)<<16)|bf16(k0), RNE
      }

      // ---- P^T B-frag via cross-quad bpermute (no barrier) ----
      short8 pb;
      {
        uint32_t e0 = (uint32_t)__builtin_amdgcn_ds_bpermute(pa0, (int)pkc[0]);
        uint32_t e1 = (uint32_t)__builtin_amdgcn_ds_bpermute(pa0, (int)pkc[1]);
        uint32_t e2 = (uint32_t)__builtin_amdgcn_ds_bpermute(pa0, (int)pkc[2]);
        uint32_t e3 = (uint32_t)__builtin_amdgcn_ds_bpermute(pa0, (int)pkc[3]);
        uint32_t f0 = (uint32_t)__builtin_amdgcn_ds_bpermute(pa1, (int)pkc[0]);
        uint32_t f1 = (uint32_t)__builtin_amdgcn_ds_bpermute(pa1, (int)pkc[1]);
        uint32_t f2 = (uint32_t)__builtin_amdgcn_ds_bpermute(pa1, (int)pkc[2]);
        uint32_t f3 = (uint32_t)__builtin_amdgcn_ds_bpermute(pa1, (int)pkc[3]);
        uint32_t w0 = __builtin_amdgcn_perm(e1, e0, sel);
        uint32_t w1 = __builtin_amdgcn_perm(e3, e2, sel);
        uint32_t w2 = __builtin_amdgcn_perm(f1, f0, sel);
        uint32_t w3 = __builtin_amdgcn_perm(f3, f2, sel);
        uint32_t tmp[4] = {w0, w1, w2, w3};
        pb = *(const short8*)tmp;  // B[k=quad*8+j][n=lm] for sk-chunk c
      }

      // ---- O^T += V^T(chunk c) . P^T(chunk c), V^T frags from LDS ----
      {
        const int ac = (c == 0) ? a0s : a1s;
#pragma unroll
        for (int nb = 0; nb < 4; ++nb) {
          short8 vb = *(const short8*)&sb[ac + nb * 1024 + 8192];
          acc[nb] = __builtin_amdgcn_mfma_f32_16x16x32_bf16(vb, pb, acc[nb], 0, 0, 0);
        }
      }
    }
  }

  // ---- each wave owns its q-rows completely: reduce l across quads, write out ----
  l_i += __shfl_xor(l_i, 16);
  l_i += __shfl_xor(l_i, 32);
  const float sc = (0.5f / 0.9f) / l_i;
  float* op = out + (((size_t)(b * Hh + h)) * SQc + qrow) * DVc;
#pragma unroll
  for (int nb = 0; nb < 4; ++nb) {
    float4 o = make_float4(acc[nb][0] * sc, acc[nb][1] * sc,
                           acc[nb][2] * sc, acc[nb][3] * sc);
    *(float4*)(op + nb * 16 + quad * 4) = o;
  }
}

extern "C" void kernel_launch(void* const* d_in, const int* in_sizes, int n_in,
                              void* d_out, int out_size, void* d_ws, size_t ws_size,
                              hipStream_t stream) {
  const float* q = (const float*)d_in[0];
  const float* k = (const float*)d_in[1];
  const float* v = (const float*)d_in[2];
  float* out = (float*)d_out;
  // ws layout: Kh (4 MB) | Kl (4 MB) | Vt (4 MB), tile-contiguous swizzled
  unsigned short* Khg = (unsigned short*)d_ws;
  unsigned short* Klg = Khg + (size_t)Hh * SKc * Dc;
  unsigned short* Vtg = Klg + (size_t)Hh * SKc * Dc;
  prep_kernel<<<dim3(Hh * 32), 256, 0, stream>>>(k, v, Khg, Klg, Vtg);
  attn_main<<<dim3(Bb * Hh * (SQc / 128)), 512, 0, stream>>>(q, Khg, Klg, Vtg, out);
}